// Round 1
// baseline (266.401 us; speedup 1.0000x reference)
//
#include <hip/hip_runtime.h>

#define CC 512
#define TT 4096
#define NB 4
#define NH 8
#define HD 64

typedef __attribute__((ext_vector_type(8))) short s16x8;
typedef __attribute__((ext_vector_type(4))) float f32x4;

// float -> bf16 bits, round-to-nearest-even (normal values; inputs are sane)
__device__ __forceinline__ short f2bf(float f) {
    unsigned u = __float_as_uint(f);
    unsigned r = (u + 0x7fffu + ((u >> 16) & 1u)) >> 16;
    return (short)r;
}

__device__ __forceinline__ void gld_lds16(const void* g, void* s) {
    __builtin_amdgcn_global_load_lds(
        (const __attribute__((address_space(1))) unsigned int*)g,
        (__attribute__((address_space(3))) unsigned int*)s, 16, 0, 0);
}

// ---------------- weight fp32 -> bf16 (4 matrices concatenated) ----------------
__global__ __launch_bounds__(256) void cvt_w_k(const float* __restrict__ w0,
                                               const float* __restrict__ w1,
                                               const float* __restrict__ w2,
                                               const float* __restrict__ w3,
                                               short* __restrict__ dst) {
    int i = blockIdx.x * 256 + threadIdx.x;  // 4*262144 total
    const float* s = (i < 262144) ? w0 : (i < 524288) ? w1 : (i < 786432) ? w2 : w3;
    dst[i] = f2bf(s[i & 262143]);
}

// ---------- transpose+convert: fp32 (B,C,T) -> bf16 (B,T,C), x and cond -------
__global__ __launch_bounds__(256) void trans_k(const float* __restrict__ x,
                                               const float* __restrict__ cond,
                                               short* __restrict__ xT,
                                               short* __restrict__ condT) {
    __shared__ float tile[64][65];
    int z = blockIdx.z;          // 0..7
    int b = z & 3;
    const float* src = (z < 4 ? x : cond) + (size_t)b * CC * TT;
    short* dst = (z < 4 ? xT : condT) + (size_t)b * TT * CC;
    int tx = threadIdx.x & 63, ty = threadIdx.x >> 6;
    int t0 = blockIdx.x * 64, c0 = blockIdx.y * 64;
#pragma unroll
    for (int r = 0; r < 64; r += 4)
        tile[ty + r][tx] = src[(size_t)(c0 + ty + r) * TT + t0 + tx];
    __syncthreads();
#pragma unroll
    for (int r = 0; r < 64; r += 4)
        dst[(size_t)(t0 + ty + r) * CC + c0 + tx] = f2bf(tile[tx][ty + r]);
}

// ---------------- 128x128x64 bf16 MFMA GEMM core ----------------
// Wm: [512][512] bf16 (o,k) row-major. Sm: [4096][512] bf16 (t,k) row-major.
// Dm: [512][4096] fp32 (o,t).  D = W * S^T + bias.
__device__ __forceinline__ void gemm128(const short* __restrict__ Wm,
                                        const short* __restrict__ Sm,
                                        const float* __restrict__ bias,
                                        float* __restrict__ Dm) {
    __shared__ short Al[128 * 64] __attribute__((aligned(16)));
    __shared__ short Bl[128 * 64] __attribute__((aligned(16)));
    const int tid = threadIdx.x;
    const int lane = tid & 63;
    const int wid = tid >> 6;
    const int o0 = blockIdx.y * 128;
    const int t0 = blockIdx.x * 128;
    const int wm = (wid >> 1) * 64;
    const int wn = (wid & 1) * 64;

    f32x4 acc[4][4];
#pragma unroll
    for (int i = 0; i < 4; i++)
#pragma unroll
        for (int j = 0; j < 4; j++) acc[i][j] = (f32x4){0.f, 0.f, 0.f, 0.f};

    const int cbase = (wid * 4) << 6;  // chunk base for this wave (64 chunks/call)

    for (int kt = 0; kt < 8; ++kt) {
        const int k0 = kt * 64;
        __syncthreads();  // previous tile's reads complete
#pragma unroll
        for (int j = 0; j < 4; ++j) {
            int c = cbase + (j << 6) + lane;   // 16B chunk index 0..1023
            int m = c >> 3, kc = c & 7;
            int kcs = kc ^ (m & 7);            // pre-swizzled source chunk
            gld_lds16(Wm + (size_t)(o0 + m) * CC + k0 + kcs * 8,
                      &Al[(cbase + (j << 6)) << 3]);
            gld_lds16(Sm + (size_t)(t0 + m) * CC + k0 + kcs * 8,
                      &Bl[(cbase + (j << 6)) << 3]);
        }
        __syncthreads();  // drains vmcnt(0): staged data visible
#pragma unroll
        for (int kk = 0; kk < 2; ++kk) {
            const int kb = kk * 32 + (lane >> 4) * 8;
            s16x8 af[4], bfr[4];
#pragma unroll
            for (int i = 0; i < 4; i++) {
                int m = wm + i * 16 + (lane & 15);
                af[i] = *(const s16x8*)&Al[(m * 64 + kb) ^ ((m & 7) << 3)];
                int n = wn + i * 16 + (lane & 15);
                bfr[i] = *(const s16x8*)&Bl[(n * 64 + kb) ^ ((n & 7) << 3)];
            }
#pragma unroll
            for (int mi = 0; mi < 4; mi++)
#pragma unroll
                for (int ni = 0; ni < 4; ni++)
                    acc[mi][ni] = __builtin_amdgcn_mfma_f32_16x16x32_bf16(
                        af[mi], bfr[ni], acc[mi][ni], 0, 0, 0);
        }
    }

    const int col = lane & 15;
    const int rg = (lane >> 4) << 2;
#pragma unroll
    for (int mi = 0; mi < 4; mi++) {
        int o = o0 + wm + mi * 16 + rg;
#pragma unroll
        for (int ni = 0; ni < 4; ni++) {
            int t = t0 + wn + ni * 16 + col;
            f32x4 a = acc[mi][ni];
#pragma unroll
            for (int r = 0; r < 4; r++)
                Dm[(size_t)(o + r) * TT + t] = a[r] + bias[o + r];
        }
    }
}

__global__ __launch_bounds__(256, 2) void gemm_qkv_k(
    const short* __restrict__ Wb, const short* __restrict__ xT,
    const short* __restrict__ condT, const float* __restrict__ bq,
    const float* __restrict__ bk, const float* __restrict__ bv,
    float* __restrict__ qkv) {
    int z = blockIdx.z, which = z >> 2, b = z & 3;
    const short* Wm = Wb + (size_t)which * CC * CC;
    const short* Sm = (which == 0 ? xT : condT) + (size_t)b * TT * CC;
    const float* bias = which == 0 ? bq : (which == 1 ? bk : bv);
    float* Dm = qkv + ((size_t)which * NB + b) * CC * TT;
    gemm128(Wm, Sm, bias, Dm);
}

__global__ __launch_bounds__(256, 2) void gemm_o_k(const short* __restrict__ Wb,
                                                   const short* __restrict__ outT,
                                                   const float* __restrict__ bo,
                                                   float* __restrict__ out) {
    int b = blockIdx.z;
    gemm128(Wb + 3 * (size_t)CC * CC, outT + (size_t)b * TT * CC, bo,
            out + (size_t)b * CC * TT);
}

// ---------------- windowed attention, fp32, thread per (b,h,t) ----------------
// q,k,v fp32 (B,C,T) at qkv[+0, +BCT, +2BCT]; writes out^T bf16 (B,T,C).
__global__ __launch_bounds__(256) void attn_k(const float* __restrict__ qkv,
                                              short* __restrict__ outT) {
    const int t = blockIdx.x * 256 + threadIdx.x;
    const int h = blockIdx.y, b = blockIdx.z;
    const size_t BCT = (size_t)NB * CC * TT;
    const float* q = qkv + ((size_t)b * CC + h * HD) * TT;
    const float* kp = qkv + BCT + ((size_t)b * CC + h * HD) * TT;
    const float* vp = qkv + 2 * BCT + ((size_t)b * CC + h * HD) * TT;
    const int s0 = t - 8;

    float dots[16];
#pragma unroll
    for (int w = 0; w < 16; w++) dots[w] = 0.f;

    for (int d = 0; d < 64; ++d) {
        float qd = q[(size_t)d * TT + t];
        const float* kr = kp + (size_t)d * TT;
#pragma unroll
        for (int w = 0; w < 16; w++) {
            int s = s0 + w;
            float kv = (s >= 0 && s < TT) ? kr[s] : 0.f;  // zero-pad => logit 0
            dots[w] = fmaf(qd, kv, dots[w]);
        }
    }
    float mx = -1e30f;
#pragma unroll
    for (int w = 0; w < 16; w++) {
        dots[w] *= 0.125f;
        mx = fmaxf(mx, dots[w]);
    }
    float sum = 0.f;
#pragma unroll
    for (int w = 0; w < 16; w++) {
        dots[w] = __expf(dots[w] - mx);
        sum += dots[w];
    }
    const float inv = 1.f / sum;

    short* ob = outT + ((size_t)b * TT + t) * CC + h * HD;
#pragma unroll
    for (int d0 = 0; d0 < 64; d0 += 8) {
        s16x8 pk;
#pragma unroll
        for (int dd = 0; dd < 8; ++dd) {
            const float* vr = vp + (size_t)(d0 + dd) * TT;
            float a = 0.f;
#pragma unroll
            for (int w = 0; w < 16; w++) {
                int s = s0 + w;
                if (s >= 0 && s < TT) a = fmaf(dots[w], vr[s], a);
            }
            a *= inv;
            pk[dd] = f2bf(a);
        }
        *(s16x8*)&ob[d0] = pk;
    }
}

extern "C" void kernel_launch(void* const* d_in, const int* in_sizes, int n_in,
                              void* d_out, int out_size, void* d_ws, size_t ws_size,
                              hipStream_t stream) {
    const float* x    = (const float*)d_in[0];
    const float* cond = (const float*)d_in[1];
    const float* Wq   = (const float*)d_in[2];
    const float* bq   = (const float*)d_in[3];
    const float* Wk   = (const float*)d_in[4];
    const float* bk   = (const float*)d_in[5];
    const float* Wv   = (const float*)d_in[6];
    const float* bv   = (const float*)d_in[7];
    const float* Wo   = (const float*)d_in[8];
    const float* bo   = (const float*)d_in[9];

    char* ws = (char*)d_ws;
    // layout: Wb(2MB) | xT(16MB) | condT(16MB) | qkv fp32 (3*32MB)
    short* Wb    = (short*)ws;
    short* xT    = (short*)(ws + 2097152);
    short* condT = (short*)(ws + 2097152 + 16777216);
    float* qkv   = (float*)(ws + 35651584);
    short* outT  = xT;  // xT dead after Q GEMM; reuse for attention output^T

    cvt_w_k<<<4096, 256, 0, stream>>>(Wq, Wk, Wv, Wo, Wb);
    trans_k<<<dim3(TT / 64, CC / 64, 8), 256, 0, stream>>>(x, cond, xT, condT);
    gemm_qkv_k<<<dim3(TT / 128, CC / 128, 12), 256, 0, stream>>>(Wb, xT, condT, bq, bk, bv, qkv);
    attn_k<<<dim3(TT / 256, NH, NB), 256, 0, stream>>>(qkv, outT);
    gemm_o_k<<<dim3(TT / 128, CC / 128, 4), 256, 0, stream>>>(Wb, outT, bo, (float*)d_out);
}

// Round 2
// 113.574 us; speedup vs baseline: 2.3456x; 2.3456x over previous
//
#include <hip/hip_runtime.h>

#define CC 512
#define TT 4096
#define NB 4
#define NH 8
#define HD 64

typedef __attribute__((ext_vector_type(8))) short s16x8;
typedef __attribute__((ext_vector_type(4))) float f32x4;

// float -> bf16 bits, round-to-nearest-even
__device__ __forceinline__ short f2bf(float f) {
    unsigned u = __float_as_uint(f);
    unsigned r = (u + 0x7fffu + ((u >> 16) & 1u)) >> 16;
    return (short)r;
}
__device__ __forceinline__ float bf2f(short s) {
    return __uint_as_float(((unsigned)(unsigned short)s) << 16);
}

__device__ __forceinline__ void gld_lds16(const void* g, void* s) {
    __builtin_amdgcn_global_load_lds(
        (const __attribute__((address_space(1))) unsigned int*)g,
        (__attribute__((address_space(3))) unsigned int*)s, 16, 0, 0);
}

// ---------------- weight fp32 -> bf16 (4 matrices concatenated) ----------------
__global__ __launch_bounds__(256) void cvt_w_k(const float* __restrict__ w0,
                                               const float* __restrict__ w1,
                                               const float* __restrict__ w2,
                                               const float* __restrict__ w3,
                                               short* __restrict__ dst) {
    int i = blockIdx.x * 256 + threadIdx.x;  // 4*262144 total
    const float* s = (i < 262144) ? w0 : (i < 524288) ? w1 : (i < 786432) ? w2 : w3;
    dst[i] = f2bf(s[i & 262143]);
}

// ---------- transpose+convert: fp32 (B,C,T) -> bf16 (B,T,C), x and cond -------
__global__ __launch_bounds__(256) void trans_k(const float* __restrict__ x,
                                               const float* __restrict__ cond,
                                               short* __restrict__ xT,
                                               short* __restrict__ condT) {
    __shared__ float tile[64][65];
    int z = blockIdx.z;          // 0..7
    int b = z & 3;
    const float* src = (z < 4 ? x : cond) + (size_t)b * CC * TT;
    short* dst = (z < 4 ? xT : condT) + (size_t)b * TT * CC;
    int tx = threadIdx.x & 63, ty = threadIdx.x >> 6;
    int t0 = blockIdx.x * 64, c0 = blockIdx.y * 64;
#pragma unroll
    for (int r = 0; r < 64; r += 4)
        tile[ty + r][tx] = src[(size_t)(c0 + ty + r) * TT + t0 + tx];
    __syncthreads();
#pragma unroll
    for (int r = 0; r < 64; r += 4)
        dst[(size_t)(t0 + ty + r) * CC + c0 + tx] = f2bf(tile[tx][ty + r]);
}

// ---------------- 128x128x64 bf16 MFMA GEMM core ----------------
// Wm: [512][512] bf16 (o,k) row-major. Sm: [4096][512] bf16 (t,k) row-major.
// TMAJOR=0: Df[o][t] fp32 = W*S^T + bias.
// TMAJOR=1: Db[t][o] bf16 = (W*S^T)^T + bias (swapped MFMA operands).
template <int TMAJOR>
__device__ __forceinline__ void gemm128(const short* __restrict__ Wm,
                                        const short* __restrict__ Sm,
                                        const float* __restrict__ bias,
                                        float* __restrict__ Df,
                                        short* __restrict__ Db) {
    __shared__ short Al[128 * 64] __attribute__((aligned(16)));
    __shared__ short Bl[128 * 64] __attribute__((aligned(16)));
    const int tid = threadIdx.x;
    const int lane = tid & 63;
    const int wid = tid >> 6;
    const int o0 = blockIdx.y * 128;
    const int t0 = blockIdx.x * 128;
    const int wm = (wid >> 1) * 64;
    const int wn = (wid & 1) * 64;

    f32x4 acc[4][4];
#pragma unroll
    for (int i = 0; i < 4; i++)
#pragma unroll
        for (int j = 0; j < 4; j++) acc[i][j] = (f32x4){0.f, 0.f, 0.f, 0.f};

    const int cbase = (wid * 4) << 6;  // chunk base for this wave (64 chunks/call)

    for (int kt = 0; kt < 8; ++kt) {
        const int k0 = kt * 64;
        __syncthreads();  // previous tile's reads complete
#pragma unroll
        for (int j = 0; j < 4; ++j) {
            int c = cbase + (j << 6) + lane;   // 16B chunk index 0..1023
            int m = c >> 3, kc = c & 7;
            int kcs = kc ^ (m & 7);            // pre-swizzled source chunk
            gld_lds16(Wm + (size_t)(o0 + m) * CC + k0 + kcs * 8,
                      &Al[(cbase + (j << 6)) << 3]);
            gld_lds16(Sm + (size_t)(t0 + m) * CC + k0 + kcs * 8,
                      &Bl[(cbase + (j << 6)) << 3]);
        }
        __syncthreads();  // drains vmcnt(0): staged data visible
#pragma unroll
        for (int kk = 0; kk < 2; ++kk) {
            const int kb = kk * 32 + (lane >> 4) * 8;
            s16x8 af[4], bfr[4];
#pragma unroll
            for (int i = 0; i < 4; i++) {
                int m = wm + i * 16 + (lane & 15);
                af[i] = *(const s16x8*)&Al[(m * 64 + kb) ^ ((m & 7) << 3)];
                int n = wn + i * 16 + (lane & 15);
                bfr[i] = *(const s16x8*)&Bl[(n * 64 + kb) ^ ((n & 7) << 3)];
            }
#pragma unroll
            for (int mi = 0; mi < 4; mi++)
#pragma unroll
                for (int ni = 0; ni < 4; ni++) {
                    if (TMAJOR)   // rows = t (bfr tile), cols = o (af tile)
                        acc[mi][ni] = __builtin_amdgcn_mfma_f32_16x16x32_bf16(
                            bfr[mi], af[ni], acc[mi][ni], 0, 0, 0);
                    else
                        acc[mi][ni] = __builtin_amdgcn_mfma_f32_16x16x32_bf16(
                            af[mi], bfr[ni], acc[mi][ni], 0, 0, 0);
                }
        }
    }

    const int col = lane & 15;
    const int rg = (lane >> 4) << 2;
    if (TMAJOR) {
#pragma unroll
        for (int ti = 0; ti < 4; ti++) {
            int t = t0 + wn + ti * 16 + rg;
#pragma unroll
            for (int oi = 0; oi < 4; oi++) {
                int o = o0 + wm + oi * 16 + col;
                float bv = bias[o];
                f32x4 a = acc[ti][oi];
#pragma unroll
                for (int r = 0; r < 4; r++)
                    Db[(size_t)(t + r) * CC + o] = f2bf(a[r] + bv);
            }
        }
    } else {
#pragma unroll
        for (int mi = 0; mi < 4; mi++) {
            int o = o0 + wm + mi * 16 + rg;
#pragma unroll
            for (int ni = 0; ni < 4; ni++) {
                int t = t0 + wn + ni * 16 + col;
                f32x4 a = acc[mi][ni];
#pragma unroll
                for (int r = 0; r < 4; r++)
                    Df[(size_t)(o + r) * TT + t] = a[r] + bias[o + r];
            }
        }
    }
}

// QKV: writes bf16 [which][b][t][C]
__global__ __launch_bounds__(256, 2) void gemm_qkv_k(
    const short* __restrict__ Wb, const short* __restrict__ xT,
    const short* __restrict__ condT, const float* __restrict__ bq,
    const float* __restrict__ bk, const float* __restrict__ bv,
    short* __restrict__ qkvT) {
    int z = blockIdx.z, which = z >> 2, b = z & 3;
    const short* Wm = Wb + (size_t)which * CC * CC;
    const short* Sm = (which == 0 ? xT : condT) + (size_t)b * TT * CC;
    const float* bias = which == 0 ? bq : (which == 1 ? bk : bv);
    short* Db = qkvT + ((size_t)which * NB + b) * TT * CC;
    gemm128<1>(Wm, Sm, bias, nullptr, Db);
}

__global__ __launch_bounds__(256, 2) void gemm_o_k(const short* __restrict__ Wb,
                                                   const short* __restrict__ outT,
                                                   const float* __restrict__ bo,
                                                   float* __restrict__ out) {
    int b = blockIdx.z;
    gemm128<0>(Wb + 3 * (size_t)CC * CC, outT + (size_t)b * TT * CC, bo,
               out + (size_t)b * CC * TT, nullptr);
}

// ---------------- windowed attention v2: LDS-staged bf16 ----------------
// qkvT: bf16 [3][B][T][C]; out: bf16 [B][T][C].
// Block = 64 threads = one (b, h, 64-t tile). LDS holds K/V band rows
// [t0-8, t0+70] (79 rows x 64ch) with 16B-chunk slot XOR swizzle c^(row&7).
__global__ __launch_bounds__(64) void attn2_k(const short* __restrict__ qkvT,
                                              short* __restrict__ outT) {
    __shared__ short kl[632 * 8] __attribute__((aligned(16)));
    __shared__ short vl[632 * 8] __attribute__((aligned(16)));
    const int lane = threadIdx.x;
    const int t0 = blockIdx.x * 64;
    const int h = blockIdx.y, b = blockIdx.z;
    const size_t BTC = (size_t)NB * TT * CC;
    const short* qg = qkvT + (size_t)b * TT * CC + h * HD;
    const short* kg = qg + BTC;
    const short* vg = qg + 2 * BTC;

    // stage K/V band
#pragma unroll
    for (int it = 0; it < 10; ++it) {
        int idx = it * 64 + lane;          // chunk index 0..631
        if (idx < 632) {
            int row = idx >> 3, s = idx & 7;
            int c = s ^ (row & 7);         // LDS slot s holds global chunk c
            int t = t0 - 8 + row;
            s16x8 kv = {0, 0, 0, 0, 0, 0, 0, 0};
            s16x8 vv = {0, 0, 0, 0, 0, 0, 0, 0};
            if (t >= 0 && t < TT) {
                kv = *(const s16x8*)&kg[(size_t)t * CC + c * 8];
                vv = *(const s16x8*)&vg[(size_t)t * CC + c * 8];
            }
            *(s16x8*)&kl[idx * 8] = kv;
            *(s16x8*)&vl[idx * 8] = vv;
        }
    }

    // own Q row -> fp32 regs
    float qf[64];
    {
        const short* qr = qg + (size_t)(t0 + lane) * CC;
#pragma unroll
        for (int c = 0; c < 8; ++c) {
            s16x8 v = *(const s16x8*)&qr[c * 8];
#pragma unroll
            for (int j = 0; j < 8; ++j) qf[c * 8 + j] = bf2f(v[j]);
        }
    }
    __syncthreads();

    float dots[16];
#pragma unroll
    for (int w = 0; w < 16; ++w) {
        const int row = lane + w;          // LDS row (t = t0-8+row)
        float acc = 0.f;
#pragma unroll
        for (int c = 0; c < 8; ++c) {
            s16x8 kv = *(const s16x8*)&kl[(row * 8 + (c ^ (row & 7))) * 8];
#pragma unroll
            for (int j = 0; j < 8; ++j) acc = fmaf(qf[c * 8 + j], bf2f(kv[j]), acc);
        }
        dots[w] = acc * 0.125f;
    }
    float mx = dots[0];
#pragma unroll
    for (int w = 1; w < 16; ++w) mx = fmaxf(mx, dots[w]);
    float sum = 0.f;
#pragma unroll
    for (int w = 0; w < 16; ++w) {
        dots[w] = __expf(dots[w] - mx);
        sum += dots[w];
    }
    const float inv = 1.f / sum;

    float of[64];
#pragma unroll
    for (int j = 0; j < 64; ++j) of[j] = 0.f;
#pragma unroll
    for (int w = 0; w < 16; ++w) {
        const int row = lane + w;
        const float p = dots[w];
#pragma unroll
        for (int c = 0; c < 8; ++c) {
            s16x8 vv = *(const s16x8*)&vl[(row * 8 + (c ^ (row & 7))) * 8];
#pragma unroll
            for (int j = 0; j < 8; ++j)
                of[c * 8 + j] = fmaf(p, bf2f(vv[j]), of[c * 8 + j]);
        }
    }
    short* ob = outT + ((size_t)b * TT + t0 + lane) * CC + h * HD;
#pragma unroll
    for (int c = 0; c < 8; ++c) {
        s16x8 pk;
#pragma unroll
        for (int j = 0; j < 8; ++j) pk[j] = f2bf(of[c * 8 + j] * inv);
        *(s16x8*)&ob[c * 8] = pk;
    }
}

extern "C" void kernel_launch(void* const* d_in, const int* in_sizes, int n_in,
                              void* d_out, int out_size, void* d_ws, size_t ws_size,
                              hipStream_t stream) {
    const float* x    = (const float*)d_in[0];
    const float* cond = (const float*)d_in[1];
    const float* Wq   = (const float*)d_in[2];
    const float* bq   = (const float*)d_in[3];
    const float* Wk   = (const float*)d_in[4];
    const float* bk   = (const float*)d_in[5];
    const float* Wv   = (const float*)d_in[6];
    const float* bv   = (const float*)d_in[7];
    const float* Wo   = (const float*)d_in[8];
    const float* bo   = (const float*)d_in[9];

    char* ws = (char*)d_ws;
    // layout: Wb(2MB) | xT(16MB) | condT(16MB) | qkvT bf16 (48MB)
    short* Wb    = (short*)ws;
    short* xT    = (short*)(ws + (2u << 20));
    short* condT = (short*)(ws + (18u << 20));
    short* qkvT  = (short*)(ws + (34u << 20));
    short* outT  = xT;  // xT dead after Q GEMM; reuse for attention output^T

    cvt_w_k<<<4096, 256, 0, stream>>>(Wq, Wk, Wv, Wo, Wb);
    trans_k<<<dim3(TT / 64, CC / 64, 8), 256, 0, stream>>>(x, cond, xT, condT);
    gemm_qkv_k<<<dim3(TT / 128, CC / 128, 12), 256, 0, stream>>>(Wb, xT, condT, bq, bk, bv, qkvT);
    attn2_k<<<dim3(TT / 64, NH, NB), 64, 0, stream>>>(qkvT, outT);
    gemm_o_k<<<dim3(TT / 128, CC / 128, 4), 256, 0, stream>>>(Wb, outT, bo, (float*)d_out);
}

// Round 3
// 94.131 us; speedup vs baseline: 2.8301x; 1.2066x over previous
//
#include <hip/hip_runtime.h>

#define CC 512
#define TT 4096
#define NB 4
#define NH 8
#define HD 64

typedef __attribute__((ext_vector_type(8))) short s16x8;
typedef __attribute__((ext_vector_type(4))) float f32x4;
typedef __attribute__((ext_vector_type(4))) unsigned int u32x4;

#if defined(__has_builtin)
#  if __has_builtin(__builtin_amdgcn_fdot2_f32_bf16)
#    define HAS_BF16_DOT2 1
#  else
#    define HAS_BF16_DOT2 0
#  endif
#else
#  define HAS_BF16_DOT2 0
#endif

// float -> bf16 bits, round-to-nearest-even
__device__ __forceinline__ short f2bf(float f) {
    unsigned u = __float_as_uint(f);
    unsigned r = (u + 0x7fffu + ((u >> 16) & 1u)) >> 16;
    return (short)r;
}
__device__ __forceinline__ float bf2f(short s) {
    return __uint_as_float(((unsigned)(unsigned short)s) << 16);
}

#if HAS_BF16_DOT2
typedef __attribute__((ext_vector_type(2))) __bf16 bf16x2;
__device__ __forceinline__ float dot2bf(unsigned a, unsigned b, float c) {
    return __builtin_amdgcn_fdot2_f32_bf16(__builtin_bit_cast(bf16x2, a),
                                           __builtin_bit_cast(bf16x2, b), c, false);
}
#else
__device__ __forceinline__ float dot2bf(unsigned a, unsigned b, float c) {
    float r = fmaf(bf2f((short)(a & 0xffffu)), bf2f((short)(b & 0xffffu)), c);
    return fmaf(bf2f((short)(a >> 16)), bf2f((short)(b >> 16)), r);
}
#endif

__device__ __forceinline__ void gld_lds16(const void* g, void* s) {
    __builtin_amdgcn_global_load_lds(
        (const __attribute__((address_space(1))) unsigned int*)g,
        (__attribute__((address_space(3))) unsigned int*)s, 16, 0, 0);
}

// ---------------- weight fp32 -> bf16 (4 matrices concatenated) ----------------
__global__ __launch_bounds__(256) void cvt_w_k(const float* __restrict__ w0,
                                               const float* __restrict__ w1,
                                               const float* __restrict__ w2,
                                               const float* __restrict__ w3,
                                               short* __restrict__ dst) {
    int i = blockIdx.x * 256 + threadIdx.x;  // 4*262144 total
    const float* s = (i < 262144) ? w0 : (i < 524288) ? w1 : (i < 786432) ? w2 : w3;
    dst[i] = f2bf(s[i & 262143]);
}

// ---------- transpose+convert: fp32 (B,C,T) -> bf16 (B,T,C), x and cond -------
__global__ __launch_bounds__(256) void trans_k(const float* __restrict__ x,
                                               const float* __restrict__ cond,
                                               short* __restrict__ xT,
                                               short* __restrict__ condT) {
    __shared__ float tile[64][65];
    int z = blockIdx.z;          // 0..7
    int b = z & 3;
    const float* src = (z < 4 ? x : cond) + (size_t)b * CC * TT;
    short* dst = (z < 4 ? xT : condT) + (size_t)b * TT * CC;
    int tx = threadIdx.x & 63, ty = threadIdx.x >> 6;
    int t0 = blockIdx.x * 64, c0 = blockIdx.y * 64;
#pragma unroll
    for (int r = 0; r < 64; r += 4)
        tile[ty + r][tx] = src[(size_t)(c0 + ty + r) * TT + t0 + tx];
    __syncthreads();
#pragma unroll
    for (int r = 0; r < 64; r += 4)
        dst[(size_t)(t0 + ty + r) * CC + c0 + tx] = f2bf(tile[tx][ty + r]);
}

// ---------------- 128x128x64 bf16 MFMA GEMM core ----------------
// Wm: [512][512] bf16 (o,k) row-major. Sm: [4096][512] bf16 (t,k) row-major.
// TMAJOR=0: Df[o][t] fp32 = W*S^T + bias.
// TMAJOR=1: Db[t][o] bf16 = (W*S^T)^T + bias (swapped MFMA operands).
template <int TMAJOR>
__device__ __forceinline__ void gemm128(const short* __restrict__ Wm,
                                        const short* __restrict__ Sm,
                                        const float* __restrict__ bias,
                                        float* __restrict__ Df,
                                        short* __restrict__ Db) {
    __shared__ short Al[128 * 64] __attribute__((aligned(16)));
    __shared__ short Bl[128 * 64] __attribute__((aligned(16)));
    const int tid = threadIdx.x;
    const int lane = tid & 63;
    const int wid = tid >> 6;
    const int o0 = blockIdx.y * 128;
    const int t0 = blockIdx.x * 128;
    const int wm = (wid >> 1) * 64;
    const int wn = (wid & 1) * 64;

    f32x4 acc[4][4];
#pragma unroll
    for (int i = 0; i < 4; i++)
#pragma unroll
        for (int j = 0; j < 4; j++) acc[i][j] = (f32x4){0.f, 0.f, 0.f, 0.f};

    const int cbase = (wid * 4) << 6;  // chunk base for this wave (64 chunks/call)

    for (int kt = 0; kt < 8; ++kt) {
        const int k0 = kt * 64;
        __syncthreads();  // previous tile's reads complete
#pragma unroll
        for (int j = 0; j < 4; ++j) {
            int c = cbase + (j << 6) + lane;   // 16B chunk index 0..1023
            int m = c >> 3, kc = c & 7;
            int kcs = kc ^ (m & 7);            // pre-swizzled source chunk
            gld_lds16(Wm + (size_t)(o0 + m) * CC + k0 + kcs * 8,
                      &Al[(cbase + (j << 6)) << 3]);
            gld_lds16(Sm + (size_t)(t0 + m) * CC + k0 + kcs * 8,
                      &Bl[(cbase + (j << 6)) << 3]);
        }
        __syncthreads();  // drains vmcnt(0): staged data visible
#pragma unroll
        for (int kk = 0; kk < 2; ++kk) {
            const int kb = kk * 32 + (lane >> 4) * 8;
            s16x8 af[4], bfr[4];
#pragma unroll
            for (int i = 0; i < 4; i++) {
                int m = wm + i * 16 + (lane & 15);
                af[i] = *(const s16x8*)&Al[(m * 64 + kb) ^ ((m & 7) << 3)];
                int n = wn + i * 16 + (lane & 15);
                bfr[i] = *(const s16x8*)&Bl[(n * 64 + kb) ^ ((n & 7) << 3)];
            }
#pragma unroll
            for (int mi = 0; mi < 4; mi++)
#pragma unroll
                for (int ni = 0; ni < 4; ni++) {
                    if (TMAJOR)   // rows = t (bfr tile), cols = o (af tile)
                        acc[mi][ni] = __builtin_amdgcn_mfma_f32_16x16x32_bf16(
                            bfr[mi], af[ni], acc[mi][ni], 0, 0, 0);
                    else
                        acc[mi][ni] = __builtin_amdgcn_mfma_f32_16x16x32_bf16(
                            af[mi], bfr[ni], acc[mi][ni], 0, 0, 0);
                }
        }
    }

    const int col = lane & 15;
    const int rg = (lane >> 4) << 2;
    if (TMAJOR) {
#pragma unroll
        for (int ti = 0; ti < 4; ti++) {
            int t = t0 + wn + ti * 16 + rg;
#pragma unroll
            for (int oi = 0; oi < 4; oi++) {
                int o = o0 + wm + oi * 16 + col;
                float bv = bias[o];
                f32x4 a = acc[ti][oi];
#pragma unroll
                for (int r = 0; r < 4; r++)
                    Db[(size_t)(t + r) * CC + o] = f2bf(a[r] + bv);
            }
        }
    } else {
#pragma unroll
        for (int mi = 0; mi < 4; mi++) {
            int o = o0 + wm + mi * 16 + rg;
#pragma unroll
            for (int ni = 0; ni < 4; ni++) {
                int t = t0 + wn + ni * 16 + col;
                f32x4 a = acc[mi][ni];
#pragma unroll
                for (int r = 0; r < 4; r++)
                    Df[(size_t)(o + r) * TT + t] = a[r] + bias[o + r];
            }
        }
    }
}

// QKV: writes bf16 [which][b][t][C]
__global__ __launch_bounds__(256, 2) void gemm_qkv_k(
    const short* __restrict__ Wb, const short* __restrict__ xT,
    const short* __restrict__ condT, const float* __restrict__ bq,
    const float* __restrict__ bk, const float* __restrict__ bv,
    short* __restrict__ qkvT) {
    int z = blockIdx.z, which = z >> 2, b = z & 3;
    const short* Wm = Wb + (size_t)which * CC * CC;
    const short* Sm = (which == 0 ? xT : condT) + (size_t)b * TT * CC;
    const float* bias = which == 0 ? bq : (which == 1 ? bk : bv);
    short* Db = qkvT + ((size_t)which * NB + b) * TT * CC;
    gemm128<1>(Wm, Sm, bias, nullptr, Db);
}

__global__ __launch_bounds__(256, 2) void gemm_o_k(const short* __restrict__ Wb,
                                                   const short* __restrict__ outT,
                                                   const float* __restrict__ bo,
                                                   float* __restrict__ out) {
    int b = blockIdx.z;
    gemm128<0>(Wb + 3 * (size_t)CC * CC, outT + (size_t)b * TT * CC, bo,
               out + (size_t)b * CC * TT, nullptr);
}

// ---------------- windowed attention v3: LDS + dot2/perm ----------------
// qkvT: bf16 [3][B][T][C]; out: bf16 [B][T][C].
// Block = 64 threads = one (b, h, 64-t tile). LDS band rows [t0-8, t0+71]
// (80 rows x 8 16B-chunks, slot XOR swizzle c^(row&7)). Q packed bf16 in regs;
// QK^T and PV via v_dot2_f32_bf16 (p packed to bf16 pairs, V paired by v_perm).
__global__ __launch_bounds__(64) void attn3_k(const short* __restrict__ qkvT,
                                              short* __restrict__ outT) {
    __shared__ unsigned kl[640 * 4] __attribute__((aligned(16)));
    __shared__ unsigned vl[640 * 4] __attribute__((aligned(16)));
    const int lane = threadIdx.x;
    const int t0 = blockIdx.x * 64;
    const int h = blockIdx.y, b = blockIdx.z;
    const size_t BTC = (size_t)NB * TT * CC;
    const short* qg = qkvT + (size_t)b * TT * CC + h * HD;
    const short* kg = qg + BTC;
    const short* vg = qg + 2 * BTC;

    // own Q row -> packed bf16 dwords (no conversion)
    u32x4 qv[8];
    {
        const u32x4* qr = (const u32x4*)(qg + (size_t)(t0 + lane) * CC);
#pragma unroll
        for (int c = 0; c < 8; ++c) qv[c] = qr[c];
    }

    // stage K/V band (80 rows x 128B each), slot-swizzled
#pragma unroll
    for (int it = 0; it < 10; ++it) {
        int idx = it * 64 + lane;          // chunk index 0..639
        int row = idx >> 3, s = idx & 7;
        int c = s ^ (row & 7);             // LDS slot s holds global chunk c
        int t = t0 - 8 + row;
        u32x4 kv = {0u, 0u, 0u, 0u};
        u32x4 vv = {0u, 0u, 0u, 0u};
        if ((unsigned)t < (unsigned)TT) {
            kv = *(const u32x4*)&kg[(size_t)t * CC + c * 8];
            vv = *(const u32x4*)&vg[(size_t)t * CC + c * 8];
        }
        *(u32x4*)&kl[idx * 4] = kv;
        *(u32x4*)&vl[idx * 4] = vv;
    }
    __syncthreads();

    // QK^T over the 16-wide window
    float dots[16];
#pragma unroll
    for (int w = 0; w < 16; ++w) {
        const int row = lane + w;          // LDS row (t = t0-8+row)
        float acc = 0.f;
#pragma unroll
        for (int c = 0; c < 8; ++c) {
            u32x4 kc = *(const u32x4*)&kl[(row * 8 + (c ^ (row & 7))) * 4];
#pragma unroll
            for (int d = 0; d < 4; ++d) acc = dot2bf(qv[c][d], kc[d], acc);
        }
        dots[w] = acc * 0.125f;
    }

    // softmax
    float mx = dots[0];
#pragma unroll
    for (int w = 1; w < 16; ++w) mx = fmaxf(mx, dots[w]);
    float e[16], sum = 0.f;
#pragma unroll
    for (int w = 0; w < 16; ++w) {
        e[w] = __expf(dots[w] - mx);
        sum += e[w];
    }
    const float inv = 1.f / sum;

    // pack normalized weights as bf16 pairs (w, w+1)
    unsigned pp[8];
#pragma unroll
    for (int i = 0; i < 8; ++i)
        pp[i] = (unsigned)(unsigned short)f2bf(e[2 * i] * inv) |
                ((unsigned)(unsigned short)f2bf(e[2 * i + 1] * inv) << 16);

    // PV: pair V rows (r0,r1) per dword via v_perm, dot2 against packed p
    float of[64];
#pragma unroll
    for (int j = 0; j < 64; ++j) of[j] = 0.f;
#pragma unroll
    for (int i = 0; i < 8; ++i) {
        const int r0 = lane + 2 * i, r1 = r0 + 1;
#pragma unroll
        for (int c = 0; c < 8; ++c) {
            u32x4 va = *(const u32x4*)&vl[(r0 * 8 + (c ^ (r0 & 7))) * 4];
            u32x4 vb = *(const u32x4*)&vl[(r1 * 8 + (c ^ (r1 & 7))) * 4];
#pragma unroll
            for (int d = 0; d < 4; ++d) {
                unsigned lo = __builtin_amdgcn_perm(vb[d], va[d], 0x05040100u);
                unsigned hi = __builtin_amdgcn_perm(vb[d], va[d], 0x07060302u);
                of[c * 8 + 2 * d]     = dot2bf(pp[i], lo, of[c * 8 + 2 * d]);
                of[c * 8 + 2 * d + 1] = dot2bf(pp[i], hi, of[c * 8 + 2 * d + 1]);
            }
        }
    }

    short* ob = outT + ((size_t)b * TT + t0 + lane) * CC + h * HD;
#pragma unroll
    for (int c = 0; c < 8; ++c) {
        s16x8 pk;
#pragma unroll
        for (int j = 0; j < 8; ++j) pk[j] = f2bf(of[c * 8 + j]);
        *(s16x8*)&ob[c * 8] = pk;
    }
}

extern "C" void kernel_launch(void* const* d_in, const int* in_sizes, int n_in,
                              void* d_out, int out_size, void* d_ws, size_t ws_size,
                              hipStream_t stream) {
    const float* x    = (const float*)d_in[0];
    const float* cond = (const float*)d_in[1];
    const float* Wq   = (const float*)d_in[2];
    const float* bq   = (const float*)d_in[3];
    const float* Wk   = (const float*)d_in[4];
    const float* bk   = (const float*)d_in[5];
    const float* Wv   = (const float*)d_in[6];
    const float* bv   = (const float*)d_in[7];
    const float* Wo   = (const float*)d_in[8];
    const float* bo   = (const float*)d_in[9];

    char* ws = (char*)d_ws;
    // layout: Wb(2MB) | xT(16MB) | condT(16MB) | qkvT bf16 (48MB)
    short* Wb    = (short*)ws;
    short* xT    = (short*)(ws + (2u << 20));
    short* condT = (short*)(ws + (18u << 20));
    short* qkvT  = (short*)(ws + (34u << 20));
    short* outT  = xT;  // xT dead after Q GEMM; reuse for attention output^T

    cvt_w_k<<<4096, 256, 0, stream>>>(Wq, Wk, Wv, Wo, Wb);
    trans_k<<<dim3(TT / 64, CC / 64, 8), 256, 0, stream>>>(x, cond, xT, condT);
    gemm_qkv_k<<<dim3(TT / 128, CC / 128, 12), 256, 0, stream>>>(Wb, xT, condT, bq, bk, bv, qkvT);
    attn3_k<<<dim3(TT / 64, NH, NB), 64, 0, stream>>>(qkvT, outT);
    gemm_o_k<<<dim3(TT / 128, CC / 128, 4), 256, 0, stream>>>(Wb, outT, bo, (float*)d_out);
}